// Round 1
// baseline (198.211 us; speedup 1.0000x reference)
//
#include <hip/hip_runtime.h>

#define B_DIM 8192
#define H_DIM 1024
#define K_DIM 2048   // I + H
#define N_DIM 4096   // 4H
#define BH (B_DIM * H_DIM)

using frag_ab = __attribute__((ext_vector_type(8))) short;   // 8 bf16 = 4 VGPR
using frag_cd = __attribute__((ext_vector_type(4))) float;

__device__ __forceinline__ unsigned short f2bf(float f) {
  union { float f; unsigned u; } x; x.f = f;
  return (unsigned short)((x.u + 0x7fffu + ((x.u >> 16) & 1u)) >> 16);
}

// ---- pack [xt | hx] -> bf16 A[8192][2048] ----
__global__ __launch_bounds__(256) void convert_A_kernel(
    const float* __restrict__ xt, const float* __restrict__ hx,
    unsigned short* __restrict__ Ab) {
  int tid = blockIdx.x * 256 + threadIdx.x;
  int flat = tid * 4;                       // < 8192*2048
  int m = flat >> 11;
  int k = flat & 2047;
  const float* src = (k < 1024) ? (xt + m * 1024 + k)
                                : (hx + m * 1024 + (k - 1024));
  float4 v = *reinterpret_cast<const float4*>(src);
  ushort4 o;
  o.x = f2bf(v.x); o.y = f2bf(v.y); o.z = f2bf(v.z); o.w = f2bf(v.w);
  *reinterpret_cast<ushort4*>(Ab + flat) = o;
}

// ---- pack gate-interleaved [W | R] -> bf16 B[4096][2048] ----
// column permutation: n' -> tile=n'>>7, c=n'&127, fi=c>>4, gate=fi&3,
//                     h = tile*32 + (fi>>2)*16 + (c&15)
__global__ __launch_bounds__(256) void convert_B_kernel(
    const float* __restrict__ w0, const float* __restrict__ w1,
    const float* __restrict__ w2, const float* __restrict__ w3,
    const float* __restrict__ r0, const float* __restrict__ r1,
    const float* __restrict__ r2, const float* __restrict__ r3,
    unsigned short* __restrict__ Bb) {
  int tid = blockIdx.x * 256 + threadIdx.x;
  int flat = tid * 4;                       // < 4096*2048
  int n = flat >> 11;
  int k = flat & 2047;
  int tile = n >> 7, c = n & 127, fi = c >> 4;
  int gate = fi & 3;
  int h = tile * 32 + (fi >> 2) * 16 + (c & 15);
  const float* wb = (gate == 0) ? w0 : (gate == 1) ? w1 : (gate == 2) ? w2 : w3;
  const float* rb = (gate == 0) ? r0 : (gate == 1) ? r1 : (gate == 2) ? r2 : r3;
  const float* src = (k < 1024) ? (wb + h * 1024 + k)
                                : (rb + h * 1024 + (k - 1024));
  float4 v = *reinterpret_cast<const float4*>(src);
  ushort4 o;
  o.x = f2bf(v.x); o.y = f2bf(v.y); o.z = f2bf(v.z); o.w = f2bf(v.w);
  *reinterpret_cast<ushort4*>(Bb + flat) = o;
}

__device__ __forceinline__ void gload_lds16(const void* g, void* l) {
  __builtin_amdgcn_global_load_lds(
      (const __attribute__((address_space(1))) unsigned int*)g,
      (__attribute__((address_space(3))) unsigned int*)l, 16, 0, 0);
}

__device__ __forceinline__ float fast_sigmoid(float x) {
  return 1.f / (1.f + __expf(-x));
}
__device__ __forceinline__ float fast_tanh(float x) {
  return 1.f - 2.f / (__expf(2.f * x) + 1.f);
}

// ---- 128x128 tile GEMM (BK=64), fused LSTM epilogue ----
__global__ __launch_bounds__(256, 3) void lstm_gemm_kernel(
    const unsigned short* __restrict__ Ab,   // [8192][2048] bf16
    const unsigned short* __restrict__ Bb,   // [4096][2048] bf16, permuted
    const float* __restrict__ cx,
    const float* __restrict__ b_f, const float* __restrict__ b_i,
    const float* __restrict__ b_o, const float* __restrict__ b_g,
    float* __restrict__ out) {
  __shared__ alignas(16) unsigned short Alds[128 * 64];
  __shared__ alignas(16) unsigned short Blds[128 * 64];

  const int bid = blockIdx.x;
  const int swz = (bid & 7) * 256 + (bid >> 3);   // 2048 wgs, 8 XCDs, bijective
  const int bm = swz >> 5;                        // 64 M-tiles
  const int bn = swz & 31;                        // 32 N-tiles

  const int t = threadIdx.x;
  const int lane = t & 63;
  const int wid = t >> 6;
  const int wr = wid >> 1, wc = wid & 1;          // 2x2 waves, 64x64 each
  const int ln = lane & 15, kh = lane >> 4;

  frag_cd acc[4][4] = {};                          // acc[m][n], n == gate

  const size_t a_tile_base = (size_t)(bm * 128) * K_DIM;
  const size_t b_tile_base = (size_t)(bn * 128) * K_DIM;
  const int srow = t >> 3;                        // 0..31
  const int scol = (t & 7) * 8;                   // bf16 elems within 64

  for (int kt = 0; kt < K_DIM / 64; ++kt) {
    const int k0 = kt * 64;
#pragma unroll
    for (int i = 0; i < 4; ++i) {
      const int row = i * 32 + srow;
      gload_lds16(Ab + a_tile_base + (size_t)row * K_DIM + k0 + scol,
                  Alds + row * 64 + scol);
      gload_lds16(Bb + b_tile_base + (size_t)row * K_DIM + k0 + scol,
                  Blds + row * 64 + scol);
    }
    __syncthreads();   // drains vmcnt: staged tile visible to all waves
#pragma unroll
    for (int kk = 0; kk < 2; ++kk) {
      frag_ab af[4], bfr[4];
#pragma unroll
      for (int m = 0; m < 4; ++m)
        af[m] = *reinterpret_cast<const frag_ab*>(
            Alds + (wr * 64 + m * 16 + ln) * 64 + kk * 32 + kh * 8);
#pragma unroll
      for (int n = 0; n < 4; ++n)
        bfr[n] = *reinterpret_cast<const frag_ab*>(
            Blds + (wc * 64 + n * 16 + ln) * 64 + kk * 32 + kh * 8);
#pragma unroll
      for (int m = 0; m < 4; ++m)
#pragma unroll
        for (int n = 0; n < 4; ++n)
          acc[m][n] = __builtin_amdgcn_mfma_f32_16x16x32_bf16(
              af[m], bfr[n], acc[m][n], 0, 0, 0);
    }
    __syncthreads();   // protect LDS before next stage
  }

  // ---- fused LSTM epilogue ----
  // lane's column: h = bn*32 + wc*16 + ln ; fragment n == gate
  const int hcol = bn * 32 + wc * 16 + ln;
  const float bfv = b_f[hcol], biv = b_i[hcol], bov = b_o[hcol], bgv = b_g[hcol];
#pragma unroll
  for (int m = 0; m < 4; ++m) {
    const int row0 = bm * 128 + wr * 64 + m * 16 + kh * 4;
#pragma unroll
    for (int j = 0; j < 4; ++j) {
      const int row = row0 + j;
      float fp = acc[m][0][j] + bfv;
      float ip = acc[m][1][j] + biv;
      float op = acc[m][2][j] + bov;
      float gp = acc[m][3][j] + bgv;
      float ft = fast_sigmoid(fp);
      float it = fast_sigmoid(ip);
      float ot = fast_sigmoid(op);
      float gt = fast_tanh(gp);
      float cold = cx[(size_t)row * H_DIM + hcol];
      float ct = ft * cold + it * gt;
      float ht = ot * fast_tanh(ct);
      out[(size_t)row * H_DIM + hcol] = ht;
      out[BH + (size_t)row * H_DIM + hcol] = ct;
    }
  }
}

extern "C" void kernel_launch(void* const* d_in, const int* in_sizes, int n_in,
                              void* d_out, int out_size, void* d_ws, size_t ws_size,
                              hipStream_t stream) {
  const float* xt   = (const float*)d_in[0];
  const float* cxp  = (const float*)d_in[1];
  const float* hx   = (const float*)d_in[2];
  const float* w_fg = (const float*)d_in[3];
  const float* w_ig = (const float*)d_in[4];
  const float* w_og = (const float*)d_in[5];
  const float* w_ci = (const float*)d_in[6];
  const float* r_fg = (const float*)d_in[7];
  const float* r_ig = (const float*)d_in[8];
  const float* r_og = (const float*)d_in[9];
  const float* r_ci = (const float*)d_in[10];
  const float* b_fg = (const float*)d_in[11];
  const float* b_ig = (const float*)d_in[12];
  const float* b_og = (const float*)d_in[13];
  const float* b_ci = (const float*)d_in[14];

  unsigned short* Ab = (unsigned short*)d_ws;                 // 33.5 MB
  unsigned short* Bb = Ab + (size_t)B_DIM * K_DIM;            // 16.8 MB
  float* out = (float*)d_out;

  convert_A_kernel<<<dim3(B_DIM * K_DIM / 4 / 256), dim3(256), 0, stream>>>(
      xt, hx, Ab);
  convert_B_kernel<<<dim3(N_DIM * K_DIM / 4 / 256), dim3(256), 0, stream>>>(
      w_fg, w_ig, w_og, w_ci, r_fg, r_ig, r_og, r_ci, Bb);
  lstm_gemm_kernel<<<dim3((B_DIM / 128) * (N_DIM / 128)), dim3(256), 0, stream>>>(
      Ab, Bb, cxp, b_fg, b_ig, b_og, b_ci, out);
}

// Round 2
// 162.909 us; speedup vs baseline: 1.2167x; 1.2167x over previous
//
#include <hip/hip_runtime.h>

#define B_DIM 8192
#define H_DIM 1024
#define K_DIM 2048   // I + H
#define N_DIM 4096   // 4H
#define BH (B_DIM * H_DIM)
#define NT (K_DIM / 64)      // 32 K-tiles
#define TSZ (256 * 64)       // elems per LDS tile buffer
#define HALFT (128 * 64)     // elems per half-tile

using frag_ab = __attribute__((ext_vector_type(8))) short;   // 8 bf16
using frag_cd = __attribute__((ext_vector_type(4))) float;

__device__ __forceinline__ unsigned short f2bf(float f) {
  union { float f; unsigned u; } x; x.f = f;
  return (unsigned short)((x.u + 0x7fffu + ((x.u >> 16) & 1u)) >> 16);
}

// ---- pack [xt | hx] -> bf16 A[8192][2048] ----
__global__ __launch_bounds__(256) void convert_A_kernel(
    const float* __restrict__ xt, const float* __restrict__ hx,
    unsigned short* __restrict__ Ab) {
  int tid = blockIdx.x * 256 + threadIdx.x;
  int flat = tid * 4;
  int m = flat >> 11;
  int k = flat & 2047;
  const float* src = (k < 1024) ? (xt + m * 1024 + k)
                                : (hx + m * 1024 + (k - 1024));
  float4 v = *reinterpret_cast<const float4*>(src);
  ushort4 o;
  o.x = f2bf(v.x); o.y = f2bf(v.y); o.z = f2bf(v.z); o.w = f2bf(v.w);
  *reinterpret_cast<ushort4*>(Ab + flat) = o;
}

// ---- pack gate-interleaved [W | R] -> bf16 B[4096][2048] ----
// output row n: tile=n>>8, c=n&255 -> gate=(c>>4)&3, h=tile*64+(c>>6)*16+(c&15)
__global__ __launch_bounds__(256) void convert_B_kernel(
    const float* __restrict__ w0, const float* __restrict__ w1,
    const float* __restrict__ w2, const float* __restrict__ w3,
    const float* __restrict__ r0, const float* __restrict__ r1,
    const float* __restrict__ r2, const float* __restrict__ r3,
    unsigned short* __restrict__ Bb) {
  int tid = blockIdx.x * 256 + threadIdx.x;
  int flat = tid * 4;
  int n = flat >> 11;
  int k = flat & 2047;
  int tile = n >> 8, c = n & 255;
  int gate = (c >> 4) & 3;
  int h = tile * 64 + ((c >> 6) << 4) + (c & 15);
  const float* wb = (gate == 0) ? w0 : (gate == 1) ? w1 : (gate == 2) ? w2 : w3;
  const float* rb = (gate == 0) ? r0 : (gate == 1) ? r1 : (gate == 2) ? r2 : r3;
  const float* src = (k < 1024) ? (wb + h * 1024 + k)
                                : (rb + h * 1024 + (k - 1024));
  float4 v = *reinterpret_cast<const float4*>(src);
  ushort4 o;
  o.x = f2bf(v.x); o.y = f2bf(v.y); o.z = f2bf(v.z); o.w = f2bf(v.w);
  *reinterpret_cast<ushort4*>(Bb + flat) = o;
}

__device__ __forceinline__ void gload_lds16(const void* g, void* l) {
  __builtin_amdgcn_global_load_lds(
      (const __attribute__((address_space(1))) unsigned int*)g,
      (__attribute__((address_space(3))) unsigned int*)l, 16, 0, 0);
}

// Stage one 128x64 half-tile (16KB): 2 gload_lds per wave, linear LDS dest,
// inverse-swizzled global source column (rule #21).
__device__ __forceinline__ void stage_half(const unsigned short* __restrict__ g,
                                           unsigned short* l, int wid, int lane) {
#pragma unroll
  for (int i = 0; i < 2; ++i) {
    const int chunk = wid * 2 + i;                       // 0..15, 8 rows each
    const int r_h = chunk * 8 + (lane >> 3);             // row in half
    const int gcol = ((lane & 7) ^ (lane >> 3)) << 3;    // swizzled col (elems)
    gload_lds16(g + (size_t)r_h * K_DIM + gcol,
                l + chunk * 512 + lane * 8);
  }
}

// Swizzled LDS fragment read: logical (row, colbyte) -> phys colbyte ^ ((row&7)<<4)
__device__ __forceinline__ frag_ab lds_frag(const unsigned short* tb, int row, int colb) {
  const char* p = reinterpret_cast<const char*>(tb) + row * 128 + (colb ^ ((row & 7) << 4));
  return *reinterpret_cast<const frag_ab*>(p);
}

__device__ __forceinline__ void bar() {
  asm volatile("" ::: "memory");
  __builtin_amdgcn_s_barrier();
  asm volatile("" ::: "memory");
}

__device__ __forceinline__ float fast_sigmoid(float x) {
  return 1.f / (1.f + __expf(-x));
}
__device__ __forceinline__ float fast_tanh(float x) {
  return 1.f - 2.f / (__expf(2.f * x) + 1.f);
}

// ---- 256x256 tile GEMM, 4-phase K-loop, counted vmcnt, fused LSTM epilogue ----
__global__ __launch_bounds__(512, 2) void lstm_gemm_kernel(
    const unsigned short* __restrict__ Ab,   // [8192][2048] bf16
    const unsigned short* __restrict__ Bb,   // [4096][2048] bf16, gate-permuted
    const float* __restrict__ cx,
    const float* __restrict__ b_f, const float* __restrict__ b_i,
    const float* __restrict__ b_o, const float* __restrict__ b_g,
    float* __restrict__ out) {
  extern __shared__ unsigned short smem[];   // 128 KiB: A[2][TSZ], B[2][TSZ]
  unsigned short* As = smem;
  unsigned short* Bs = smem + 2 * TSZ;

  const int bid = blockIdx.x;
  const int swz = (bid & 7) * 64 + (bid >> 3);    // 512 wgs % 8 == 0: bijective
  const int bm = swz >> 4;                        // 32 M-tiles
  const int bn = swz & 15;                        // 16 N-tiles

  const int tid = threadIdx.x;
  const int lane = tid & 63;
  const int wid = tid >> 6;
  const int wr = wid >> 2, wc = wid & 3;          // 2x4 waves, 128x64 each
  const int ln = lane & 15, kh = lane >> 4;

  const unsigned short* Ag = Ab + (size_t)(bm * 256) * K_DIM;
  const unsigned short* Bg = Bb + (size_t)(bn * 256) * K_DIM;

  frag_cd acc[8][4] = {};
  frag_ab Af[4][2], Bf[4][2];

  // ---- prologue: K-tile 0 (4 halves) + B-halves of K-tile 1 ----
  stage_half(Ag, As, wid, lane);
  stage_half(Ag + 128 * K_DIM, As + HALFT, wid, lane);
  stage_half(Bg, Bs, wid, lane);
  stage_half(Bg + 128 * K_DIM, Bs + HALFT, wid, lane);
  stage_half(Bg + 64, Bs + TSZ, wid, lane);
  stage_half(Bg + 64 + 128 * K_DIM, Bs + TSZ + HALFT, wid, lane);
  asm volatile("s_waitcnt vmcnt(4)" ::: "memory");   // K0 landed; B(1) in flight
  __builtin_amdgcn_s_barrier();
  asm volatile("" ::: "memory");

  const int arow0 = wr * 128 + ln;
  const int brow0 = wc * 64 + ln;
  const int cb = kh * 16;

  for (int t = 0; t < NT; ++t) {
    unsigned short* Ac = As + (t & 1) * TSZ;
    unsigned short* Bc = Bs + (t & 1) * TSZ;
    unsigned short* An = As + ((t & 1) ^ 1) * TSZ;

    // ---- P1: read A m0..3, B n0..1; stage A-h0(t+1) ----
#pragma unroll
    for (int m = 0; m < 4; ++m)
#pragma unroll
      for (int kk = 0; kk < 2; ++kk)
        Af[m][kk] = lds_frag(Ac, arow0 + m * 16, kk * 64 + cb);
#pragma unroll
    for (int n = 0; n < 2; ++n)
#pragma unroll
      for (int kk = 0; kk < 2; ++kk)
        Bf[n][kk] = lds_frag(Bc, brow0 + n * 16, kk * 64 + cb);
    if (t + 1 < NT) stage_half(Ag + (t + 1) * 64, An, wid, lane);
    bar();
    __builtin_amdgcn_s_setprio(1);
#pragma unroll
    for (int m = 0; m < 4; ++m)
#pragma unroll
      for (int n = 0; n < 2; ++n)
#pragma unroll
        for (int kk = 0; kk < 2; ++kk)
          acc[m][n] = __builtin_amdgcn_mfma_f32_16x16x32_bf16(
              Af[m][kk], Bf[n][kk], acc[m][n], 0, 0, 0);
    __builtin_amdgcn_s_setprio(0);
    bar();

    // ---- P2: read B n2..3; stage A-h1(t+1) ----
#pragma unroll
    for (int n = 2; n < 4; ++n)
#pragma unroll
      for (int kk = 0; kk < 2; ++kk)
        Bf[n][kk] = lds_frag(Bc, brow0 + n * 16, kk * 64 + cb);
    if (t + 1 < NT) stage_half(Ag + (t + 1) * 64 + 128 * K_DIM, An + HALFT, wid, lane);
    bar();
    __builtin_amdgcn_s_setprio(1);
#pragma unroll
    for (int m = 0; m < 4; ++m)
#pragma unroll
      for (int n = 2; n < 4; ++n)
#pragma unroll
        for (int kk = 0; kk < 2; ++kk)
          acc[m][n] = __builtin_amdgcn_mfma_f32_16x16x32_bf16(
              Af[m][kk], Bf[n][kk], acc[m][n], 0, 0, 0);
    __builtin_amdgcn_s_setprio(0);
    bar();

    // ---- P3: read A m4..7; stage B-h0(t+2) (t's B-h0 dead after P2) ----
#pragma unroll
    for (int m = 0; m < 4; ++m)
#pragma unroll
      for (int kk = 0; kk < 2; ++kk)
        Af[m][kk] = lds_frag(Ac, arow0 + 64 + m * 16, kk * 64 + cb);
    if (t + 2 < NT) stage_half(Bg + (t + 2) * 64, Bc, wid, lane);
    bar();
    __builtin_amdgcn_s_setprio(1);
#pragma unroll
    for (int m = 0; m < 4; ++m)
#pragma unroll
      for (int n = 2; n < 4; ++n)
#pragma unroll
        for (int kk = 0; kk < 2; ++kk)
          acc[4 + m][n] = __builtin_amdgcn_mfma_f32_16x16x32_bf16(
              Af[m][kk], Bf[n][kk], acc[4 + m][n], 0, 0, 0);
    __builtin_amdgcn_s_setprio(0);
    bar();

    // ---- P4: stage B-h1(t+2); boundary wait vmcnt(4) (never 0 mid-loop) ----
    if (t + 2 < NT) stage_half(Bg + (t + 2) * 64 + 128 * K_DIM, Bc + HALFT, wid, lane);
    bar();
    __builtin_amdgcn_s_setprio(1);
#pragma unroll
    for (int m = 0; m < 4; ++m)
#pragma unroll
      for (int n = 0; n < 2; ++n)
#pragma unroll
        for (int kk = 0; kk < 2; ++kk)
          acc[4 + m][n] = __builtin_amdgcn_mfma_f32_16x16x32_bf16(
              Af[m][kk], Bf[n][kk], acc[4 + m][n], 0, 0, 0);
    __builtin_amdgcn_s_setprio(0);
    if (t < NT - 2) {
      // need t+1's 8 loads landed; t+2's 4 B-loads stay in flight
      asm volatile("s_waitcnt vmcnt(4)" ::: "memory");
      __builtin_amdgcn_s_barrier();
      asm volatile("" ::: "memory");
    } else if (t == NT - 2) {
      asm volatile("s_waitcnt vmcnt(0)" ::: "memory");
      __builtin_amdgcn_s_barrier();
      asm volatile("" ::: "memory");
    }
  }

  // ---- fused LSTM epilogue: n-frag == gate, h = bn*64 + wc*16 + ln ----
  const int hcol = bn * 64 + wc * 16 + ln;
  const float bfv = b_f[hcol], biv = b_i[hcol], bov = b_o[hcol], bgv = b_g[hcol];
  const int row_base = bm * 256 + wr * 128 + kh * 4;
#pragma unroll
  for (int mi = 0; mi < 8; ++mi) {
#pragma unroll
    for (int j = 0; j < 4; ++j) {
      const int row = row_base + mi * 16 + j;
      float fp = acc[mi][0][j] + bfv;
      float ip = acc[mi][1][j] + biv;
      float op = acc[mi][2][j] + bov;
      float gp = acc[mi][3][j] + bgv;
      float ft = fast_sigmoid(fp);
      float it = fast_sigmoid(ip);
      float ot = fast_sigmoid(op);
      float gt = fast_tanh(gp);
      float cold = cx[(size_t)row * H_DIM + hcol];
      float ct = ft * cold + it * gt;
      float ht = ot * fast_tanh(ct);
      out[(size_t)row * H_DIM + hcol] = ht;
      out[BH + (size_t)row * H_DIM + hcol] = ct;
    }
  }
}

extern "C" void kernel_launch(void* const* d_in, const int* in_sizes, int n_in,
                              void* d_out, int out_size, void* d_ws, size_t ws_size,
                              hipStream_t stream) {
  const float* xt   = (const float*)d_in[0];
  const float* cxp  = (const float*)d_in[1];
  const float* hx   = (const float*)d_in[2];
  const float* w_fg = (const float*)d_in[3];
  const float* w_ig = (const float*)d_in[4];
  const float* w_og = (const float*)d_in[5];
  const float* w_ci = (const float*)d_in[6];
  const float* r_fg = (const float*)d_in[7];
  const float* r_ig = (const float*)d_in[8];
  const float* r_og = (const float*)d_in[9];
  const float* r_ci = (const float*)d_in[10];
  const float* b_fg = (const float*)d_in[11];
  const float* b_ig = (const float*)d_in[12];
  const float* b_og = (const float*)d_in[13];
  const float* b_ci = (const float*)d_in[14];

  unsigned short* Abf = (unsigned short*)d_ws;                // 33.5 MB
  unsigned short* Bbf = Abf + (size_t)B_DIM * K_DIM;          // 16.8 MB
  float* out = (float*)d_out;

  convert_A_kernel<<<dim3(B_DIM * K_DIM / 4 / 256), dim3(256), 0, stream>>>(
      xt, hx, Abf);
  convert_B_kernel<<<dim3(N_DIM * K_DIM / 4 / 256), dim3(256), 0, stream>>>(
      w_fg, w_ig, w_og, w_ci, r_fg, r_ig, r_og, r_ci, Bbf);
  lstm_gemm_kernel<<<dim3((B_DIM / 256) * (N_DIM / 256)), dim3(512),
                     131072, stream>>>(
      Abf, Bbf, cxp, b_fg, b_ig, b_og, b_ci, out);
}

// Round 3
// 154.597 us; speedup vs baseline: 1.2821x; 1.0538x over previous
//
#include <hip/hip_runtime.h>

#define B_DIM 8192
#define H_DIM 1024
#define K_DIM 2048   // I + H
#define N_DIM 4096   // 4H
#define BH (B_DIM * H_DIM)
#define NT 32                // K-tiles (BK=64)
#define TSZ (256 * 64)       // elems per LDS tile buffer (32 KB)
#define HALFT (128 * 64)     // elems per half-tile

using frag_ab = __attribute__((ext_vector_type(8))) short;   // 8 bf16
using frag_cd = __attribute__((ext_vector_type(4))) float;

__device__ __forceinline__ unsigned short f2bf(float f) {
  union { float f; unsigned u; } x; x.f = f;
  return (unsigned short)((x.u + 0x7fffu + ((x.u >> 16) & 1u)) >> 16);
}

// ---- pack [xt | hx] -> bf16 A[8192][2048] ----
__global__ __launch_bounds__(256) void convert_A_kernel(
    const float* __restrict__ xt, const float* __restrict__ hx,
    unsigned short* __restrict__ Ab) {
  int tid = blockIdx.x * 256 + threadIdx.x;
  int flat = tid * 4;
  int m = flat >> 11;
  int k = flat & 2047;
  const float* src = (k < 1024) ? (xt + m * 1024 + k)
                                : (hx + m * 1024 + (k - 1024));
  float4 v = *reinterpret_cast<const float4*>(src);
  ushort4 o;
  o.x = f2bf(v.x); o.y = f2bf(v.y); o.z = f2bf(v.z); o.w = f2bf(v.w);
  *reinterpret_cast<ushort4*>(Ab + flat) = o;
}

// ---- pack gate-interleaved [W | R] -> bf16 B[4096][2048] ----
// output row n: tile=n>>8, c=n&255 -> gate=(c>>4)&3, h=tile*64+(c>>6)*16+(c&15)
__global__ __launch_bounds__(256) void convert_B_kernel(
    const float* __restrict__ w0, const float* __restrict__ w1,
    const float* __restrict__ w2, const float* __restrict__ w3,
    const float* __restrict__ r0, const float* __restrict__ r1,
    const float* __restrict__ r2, const float* __restrict__ r3,
    unsigned short* __restrict__ Bb) {
  int tid = blockIdx.x * 256 + threadIdx.x;
  int flat = tid * 4;
  int n = flat >> 11;
  int k = flat & 2047;
  int tile = n >> 8, c = n & 255;
  int gate = (c >> 4) & 3;
  int h = tile * 64 + ((c >> 6) << 4) + (c & 15);
  const float* wb = (gate == 0) ? w0 : (gate == 1) ? w1 : (gate == 2) ? w2 : w3;
  const float* rb = (gate == 0) ? r0 : (gate == 1) ? r1 : (gate == 2) ? r2 : r3;
  const float* src = (k < 1024) ? (wb + h * 1024 + k)
                                : (rb + h * 1024 + (k - 1024));
  float4 v = *reinterpret_cast<const float4*>(src);
  ushort4 o;
  o.x = f2bf(v.x); o.y = f2bf(v.y); o.z = f2bf(v.z); o.w = f2bf(v.w);
  *reinterpret_cast<ushort4*>(Bb + flat) = o;
}

__device__ __forceinline__ void gload_lds16(const void* g, void* l) {
  __builtin_amdgcn_global_load_lds(
      (const __attribute__((address_space(1))) unsigned int*)g,
      (__attribute__((address_space(3))) unsigned int*)l, 16, 0, 0);
}

__device__ __forceinline__ frag_ab ldsr(const unsigned short* buf, int byteoff) {
  return *reinterpret_cast<const frag_ab*>(
      reinterpret_cast<const char*>(buf) + byteoff);
}

__device__ __forceinline__ float fast_sigmoid(float x) {
  return 1.f / (1.f + __expf(-x));
}
__device__ __forceinline__ float fast_tanh(float x) {
  return 1.f - 2.f / (__expf(2.f * x) + 1.f);
}

#define CBAR asm volatile("" ::: "memory")
#define SBAR do { CBAR; __builtin_amdgcn_s_barrier(); CBAR; } while (0)

// One K-tile = 4 phases. Each phase: {ds_reads, stage ONE half-tile, barrier,
// MFMA (setprio-wrapped)}. Single barrier per phase: every stage target's last
// reader is >=2 phases back (protected by intervening barrier + data-dep).
// Stage plan: Q1: B(t+1)h1 -> Bnx+HALFT | Q2: A(t+1)h0 -> Anx |
//             Q3: A(t+1)h1 -> Anx+HALFT | Q4: B(t+2)h0 -> Bc ; then vmcnt.
#define TILE_BODY(Ac, Bc, Anx, Bnx, tt, S1, S2, S3, S4, DO_VM2, DO_VM0)        \
  {                                                                            \
    /* ---- Q1: kk0 reads (8), stage B(t+1)h1 ---- */                          \
    _Pragma("unroll") for (int m = 0; m < 4; ++m)                              \
        Af0[m] = ldsr(Ac, (arow + m * 16) * 128 + c0);                         \
    _Pragma("unroll") for (int n = 0; n < 4; ++n)                              \
        Bf0[n] = ldsr(Bc, (brow + n * 16) * 128 + c0);                         \
    if (S1) stage(Bg + 128 * K_DIM + (size_t)((tt) + 1) * 64, (Bnx) + HALFT);  \
    SBAR;                                                                      \
    __builtin_amdgcn_s_setprio(1);                                             \
    _Pragma("unroll") for (int m = 0; m < 4; ++m)                              \
        _Pragma("unroll") for (int n = 0; n < 4; ++n)                          \
            acc[m][n] = __builtin_amdgcn_mfma_f32_16x16x32_bf16(               \
                Af0[m], Bf0[n], acc[m][n], 0, 0, 0);                           \
    __builtin_amdgcn_s_setprio(0);                                             \
    /* ---- Q2: kk1 reads (8), stage A(t+1)h0 ---- */                          \
    _Pragma("unroll") for (int m = 0; m < 4; ++m)                              \
        Af1[m] = ldsr(Ac, (arow + m * 16) * 128 + c1);                         \
    _Pragma("unroll") for (int n = 0; n < 4; ++n)                              \
        Bf1[n] = ldsr(Bc, (brow + n * 16) * 128 + c1);                         \
    if (S2) stage(Ag + (size_t)((tt) + 1) * 64, (Anx));                        \
    SBAR;                                                                      \
    __builtin_amdgcn_s_setprio(1);                                             \
    _Pragma("unroll") for (int m = 0; m < 4; ++m)                              \
        _Pragma("unroll") for (int n = 0; n < 4; ++n)                          \
            acc[m][n] = __builtin_amdgcn_mfma_f32_16x16x32_bf16(               \
                Af1[m], Bf1[n], acc[m][n], 0, 0, 0);                           \
    __builtin_amdgcn_s_setprio(0);                                             \
    /* ---- Q3: A rows +64 kk0 (4 reads), stage A(t+1)h1 ---- */               \
    _Pragma("unroll") for (int m = 0; m < 4; ++m)                              \
        Af0[m] = ldsr(Ac, (arow + 64 + m * 16) * 128 + c0);                    \
    if (S3) stage(Ag + 128 * K_DIM + (size_t)((tt) + 1) * 64, (Anx) + HALFT);  \
    SBAR;                                                                      \
    __builtin_amdgcn_s_setprio(1);                                             \
    _Pragma("unroll") for (int m = 0; m < 4; ++m)                              \
        _Pragma("unroll") for (int n = 0; n < 4; ++n)                          \
            acc[4 + m][n] = __builtin_amdgcn_mfma_f32_16x16x32_bf16(           \
                Af0[m], Bf0[n], acc[4 + m][n], 0, 0, 0);                       \
    __builtin_amdgcn_s_setprio(0);                                             \
    /* ---- Q4: A rows +64 kk1 (4 reads), stage B(t+2)h0 ---- */               \
    _Pragma("unroll") for (int m = 0; m < 4; ++m)                              \
        Af1[m] = ldsr(Ac, (arow + 64 + m * 16) * 128 + c1);                    \
    if (S4) stage(Bg + (size_t)((tt) + 2) * 64, (Bc));                        \
    SBAR;                                                                      \
    __builtin_amdgcn_s_setprio(1);                                             \
    _Pragma("unroll") for (int m = 0; m < 4; ++m)                              \
        _Pragma("unroll") for (int n = 0; n < 4; ++n)                          \
            acc[4 + m][n] = __builtin_amdgcn_mfma_f32_16x16x32_bf16(           \
                Af1[m], Bf1[n], acc[4 + m][n], 0, 0, 0);                       \
    __builtin_amdgcn_s_setprio(0);                                             \
    if (DO_VM2) asm volatile("s_waitcnt vmcnt(2)" ::: "memory");               \
    if (DO_VM0) asm volatile("s_waitcnt vmcnt(0)" ::: "memory");               \
  }

// ---- 256x256 tile GEMM, 1-barrier phases, counted vmcnt, fused LSTM ----
__global__ __launch_bounds__(512, 2) void lstm_gemm_kernel(
    const unsigned short* __restrict__ Ab,   // [8192][2048] bf16
    const unsigned short* __restrict__ Bb,   // [4096][2048] bf16, gate-permuted
    const float* __restrict__ cx,
    const float* __restrict__ b_f, const float* __restrict__ b_i,
    const float* __restrict__ b_o, const float* __restrict__ b_g,
    float* __restrict__ out) {
  extern __shared__ unsigned short smem[];   // 128 KiB
  unsigned short* const As0 = smem;
  unsigned short* const As1 = smem + TSZ;
  unsigned short* const Bs0 = smem + 2 * TSZ;
  unsigned short* const Bs1 = smem + 3 * TSZ;

  const int bid = blockIdx.x;
  const int swz = (bid & 7) * 64 + (bid >> 3);    // 512 wgs % 8 == 0: bijective
  const int bm = swz >> 4;                        // 32 M-tiles
  const int bn = swz & 15;                        // 16 N-tiles

  const int tid = threadIdx.x;
  const int lane = tid & 63;
  const int wid = tid >> 6;
  const int wr = wid >> 2, wc = wid & 3;          // 2x4 waves, 128x64 each
  const int ln = lane & 15, kh = lane >> 4;

  const unsigned short* Ag = Ab + (size_t)(bm * 256) * K_DIM;
  const unsigned short* Bg = Bb + (size_t)(bn * 256) * K_DIM;

  // stage invariants: wave covers 16 rows of a 128-row half (2 gloads)
  const int srow = wid * 16 + (lane >> 3);
  const size_t gs0 = (size_t)srow * K_DIM + (((lane & 7) ^ (lane >> 3)) << 3);
  const size_t gs1 = gs0 + (size_t)8 * K_DIM;
  const int ld0 = wid * 2048 + lane * 16;         // LDS byte offsets (linear)
  const int ld1 = ld0 + 1024;
  auto stage = [&](const unsigned short* g, unsigned short* l) {
    gload_lds16(g + gs0, reinterpret_cast<char*>(l) + ld0);
    gload_lds16(g + gs1, reinterpret_cast<char*>(l) + ld1);
  };

  // read invariants (byte offsets; XOR swizzle with loop-invariant key)
  const int inv = (ln & 7) << 4;
  const int c0 = (kh * 16) ^ inv;                 // kk0 column
  const int c1 = (64 + kh * 16) ^ inv;            // kk1 column
  const int arow = wr * 128 + ln;
  const int brow = wc * 64 + ln;

  frag_cd acc[8][4] = {};
  frag_ab Af0[4], Af1[4], Bf0[4], Bf1[4];

  // ---- prologue: A(0), B(0) full + B(1)h0 ----
  stage(Ag, As0);
  stage(Ag + 128 * K_DIM, As0 + HALFT);
  stage(Bg, Bs0);
  stage(Bg + 128 * K_DIM, Bs0 + HALFT);
  stage(Bg + 64, Bs1);                            // B(1)h0
  asm volatile("s_waitcnt vmcnt(2)" ::: "memory");
  SBAR;

  // ---- main loop: 2 K-tiles per iter, static buffers ----
  for (int u = 0; u < 15; ++u) {
    const int e = 2 * u;
    TILE_BODY(As0, Bs0, As1, Bs1, e, 1, 1, 1, 1, 1, 0);
    TILE_BODY(As1, Bs1, As0, Bs0, e + 1, 1, 1, 1, 1, 1, 0);
  }
  // t=30: stage B(31)h1 + A(31); skip B(32); drain all
  TILE_BODY(As0, Bs0, As1, Bs1, 30, 1, 1, 1, 0, 0, 1);
  // t=31: pure compute
  TILE_BODY(As1, Bs1, As0, Bs0, 31, 0, 0, 0, 0, 0, 0);

  // ---- fused LSTM epilogue: n-frag == gate, h = bn*64 + wc*16 + ln ----
  const int hcol = bn * 64 + wc * 16 + ln;
  const float bfv = b_f[hcol], biv = b_i[hcol], bov = b_o[hcol], bgv = b_g[hcol];
  const int row_base = bm * 256 + wr * 128 + kh * 4;
#pragma unroll
  for (int mi = 0; mi < 8; ++mi) {
#pragma unroll
    for (int j = 0; j < 4; ++j) {
      const int row = row_base + mi * 16 + j;
      float fp = acc[mi][0][j] + bfv;
      float ip = acc[mi][1][j] + biv;
      float op = acc[mi][2][j] + bov;
      float gp = acc[mi][3][j] + bgv;
      float ft = fast_sigmoid(fp);
      float it = fast_sigmoid(ip);
      float ot = fast_sigmoid(op);
      float gt = fast_tanh(gp);
      float cold = cx[(size_t)row * H_DIM + hcol];
      float ct = ft * cold + it * gt;
      float ht = ot * fast_tanh(ct);
      out[(size_t)row * H_DIM + hcol] = ht;
      out[BH + (size_t)row * H_DIM + hcol] = ct;
    }
  }
}

extern "C" void kernel_launch(void* const* d_in, const int* in_sizes, int n_in,
                              void* d_out, int out_size, void* d_ws, size_t ws_size,
                              hipStream_t stream) {
  const float* xt   = (const float*)d_in[0];
  const float* cxp  = (const float*)d_in[1];
  const float* hx   = (const float*)d_in[2];
  const float* w_fg = (const float*)d_in[3];
  const float* w_ig = (const float*)d_in[4];
  const float* w_og = (const float*)d_in[5];
  const float* w_ci = (const float*)d_in[6];
  const float* r_fg = (const float*)d_in[7];
  const float* r_ig = (const float*)d_in[8];
  const float* r_og = (const float*)d_in[9];
  const float* r_ci = (const float*)d_in[10];
  const float* b_fg = (const float*)d_in[11];
  const float* b_ig = (const float*)d_in[12];
  const float* b_og = (const float*)d_in[13];
  const float* b_ci = (const float*)d_in[14];

  unsigned short* Abf = (unsigned short*)d_ws;                // 33.5 MB
  unsigned short* Bbf = Abf + (size_t)B_DIM * K_DIM;          // 16.8 MB
  float* out = (float*)d_out;

  convert_A_kernel<<<dim3(B_DIM * K_DIM / 4 / 256), dim3(256), 0, stream>>>(
      xt, hx, Abf);
  convert_B_kernel<<<dim3(N_DIM * K_DIM / 4 / 256), dim3(256), 0, stream>>>(
      w_fg, w_ig, w_og, w_ci, r_fg, r_ig, r_og, r_ci, Bbf);
  lstm_gemm_kernel<<<dim3((B_DIM / 256) * (N_DIM / 256)), dim3(512),
                     131072, stream>>>(
      Abf, Bbf, cxp, b_fg, b_ig, b_og, b_ci, out);
}